// Round 13
// baseline (44.152 us; speedup 1.0000x reference)
//
#include <hip/hip_runtime.h>
#include <stdint.h>

// Two-kernel 3x3 neighborhood-attention.
//  K1 coef3_kernel: block = one image row; 4 waves = channel quarters, each
//    SELF-PACED (no per-chunk barriers). Wave-private triple-buffered LDS
//    (2ch x 3 nbr rows per chunk, 8 chunks), prefetch 2 chunks ahead with
//    counted s_waitcnt vmcnt(14) (T4: loads stay in flight across consume).
//    ref loads direct (center-only), double-buffered in named regs.
//    Lane owns 4 px: float4 LDS read + 2 edge scalars per row. One end-of-
//    kernel cross-wave reduce through LDS (aliased with staging) + softmax.
//  K2 apply_kernel: float4 streaming out = exp(-(nbr-ref)^2)*sum_k coef_k*nbr_k.
// Shapes: [b=2, c=64, h=256, w=256] fp32.

constexpr int C = 64, H = 256, W = 256, HW = H * W;
constexpr int B = 2, PIX = B * HW;

typedef const __attribute__((address_space(1))) void* gas_ptr;
typedef __attribute__((address_space(3))) void* las_ptr;

// LDS geometry (floats): per-wave stage region = 3 slots x 2 ch x 3 rows x 264
// (264 = 4 pad + 256 + 4 pad). Reduce region = 19 x 4 waves x 256 aliases it.
constexpr int RSTRIDE = 264;
constexpr int WREGION = 3 * 2 * 3 * RSTRIDE;   // 4752 floats per wave
constexpr int SMEMF   = 19 * 4 * 256;          // 19456 floats (77824 B) total

// ---------------- K1: coefficient kernel (self-paced waves) ----------------
__global__ __launch_bounds__(256) void coef3_kernel(const float* __restrict__ nbr,
                                                    const float* __restrict__ ref,
                                                    float* __restrict__ coef) {
  __shared__ float smem[SMEMF];

  const int tid  = threadIdx.x;
  const int lane = tid & 63;
  const int wv   = tid >> 6;          // channel quarter 0..3

  // XCD band swizzle: 512 blocks, bijective
  const int by = ((blockIdx.x & 7) << 6) | (blockIdx.x >> 3);
  const int b  = by >> 8;
  const int y  = by & 255;
  const int ym = (y == 0)     ? 1     : y - 1;   // jnp reflect
  const int yp = (y == H - 1) ? H - 2 : y + 1;

  const float* nbase = nbr + (size_t)b * C * HW;
  const float* rrow  = ref + (size_t)b * C * HW + y * W;   // + c*HW + x
  const int rowoff[3] = {ym * W, y * W, yp * W};

  float* ws = smem + wv * WREGION;
  const int c0 = wv * 16;             // this wave's first channel
  const int x0 = lane * 4;            // lane owns px x0..x0+3

  // issue 6 global_load_lds for chunk i into slot s (wave-private)
  auto stage = [&](int i, int s) {
#pragma unroll
    for (int u = 0; u < 2; ++u) {
      const float* nc = nbase + (size_t)(c0 + i * 2 + u) * HW;
      float* lb = ws + ((s * 2 + u) * 3) * RSTRIDE + 4;   // row 0 data start
#pragma unroll
      for (int r = 0; r < 3; ++r) {
        __builtin_amdgcn_global_load_lds((gas_ptr)(nc + rowoff[r] + lane * 4),
                                         (las_ptr)(lb + r * RSTRIDE), 16, 0, 0);
      }
    }
  };

  float dt[4][9], sq[4][9], sr4[4];
#pragma unroll
  for (int j = 0; j < 4; ++j) {
    sr4[j] = 0.f;
#pragma unroll
    for (int k = 0; k < 9; ++k) { dt[j][k] = 0.f; sq[j][k] = 0.f; }
  }

  // consume chunk in slot s; rf0/rf1 = ref float4 for the 2 channels
  auto consume = [&](int s, const float4 rf0, const float4 rf1) {
#pragma unroll
    for (int u = 0; u < 2; ++u) {
      const float4 rf = u ? rf1 : rf0;
      const float* base = ws + ((s * 2 + u) * 3) * RSTRIDE + 4;
#pragma unroll
      for (int r = 0; r < 3; ++r) {
        const float* row = base + r * RSTRIDE;
        const float4 v = *(const float4*)(row + x0);
        float vL = row[x0 - 1];          // pad-safe (garbage only at lane 0)
        float vR = row[x0 + 4];          // pad-safe (garbage only at lane 63)
        if (lane == 0)  vL = v.y;        // reflect: x=-1 -> 1
        if (lane == 63) vR = v.z;        // reflect: x=256 -> 254
        const int k = r * 3;
        // px0 window (vL, v.x, v.y)
        dt[0][k+0] = fmaf(rf.x, vL,  dt[0][k+0]); sq[0][k+0] = fmaf(vL,  vL,  sq[0][k+0]);
        dt[0][k+1] = fmaf(rf.x, v.x, dt[0][k+1]); sq[0][k+1] = fmaf(v.x, v.x, sq[0][k+1]);
        dt[0][k+2] = fmaf(rf.x, v.y, dt[0][k+2]); sq[0][k+2] = fmaf(v.y, v.y, sq[0][k+2]);
        // px1 window (v.x, v.y, v.z)
        dt[1][k+0] = fmaf(rf.y, v.x, dt[1][k+0]); sq[1][k+0] = fmaf(v.x, v.x, sq[1][k+0]);
        dt[1][k+1] = fmaf(rf.y, v.y, dt[1][k+1]); sq[1][k+1] = fmaf(v.y, v.y, sq[1][k+1]);
        dt[1][k+2] = fmaf(rf.y, v.z, dt[1][k+2]); sq[1][k+2] = fmaf(v.z, v.z, sq[1][k+2]);
        // px2 window (v.y, v.z, v.w)
        dt[2][k+0] = fmaf(rf.z, v.y, dt[2][k+0]); sq[2][k+0] = fmaf(v.y, v.y, sq[2][k+0]);
        dt[2][k+1] = fmaf(rf.z, v.z, dt[2][k+1]); sq[2][k+1] = fmaf(v.z, v.z, sq[2][k+1]);
        dt[2][k+2] = fmaf(rf.z, v.w, dt[2][k+2]); sq[2][k+2] = fmaf(v.w, v.w, sq[2][k+2]);
        // px3 window (v.z, v.w, vR)
        dt[3][k+0] = fmaf(rf.w, v.z, dt[3][k+0]); sq[3][k+0] = fmaf(v.z, v.z, sq[3][k+0]);
        dt[3][k+1] = fmaf(rf.w, v.w, dt[3][k+1]); sq[3][k+1] = fmaf(v.w, v.w, sq[3][k+1]);
        dt[3][k+2] = fmaf(rf.w, vR,  dt[3][k+2]); sq[3][k+2] = fmaf(vR,  vR,  sq[3][k+2]);
      }
      sr4[0] = fmaf(rf.x, rf.x, sr4[0]);
      sr4[1] = fmaf(rf.y, rf.y, sr4[1]);
      sr4[2] = fmaf(rf.z, rf.z, sr4[2]);
      sr4[3] = fmaf(rf.w, rf.w, sr4[3]);
    }
  };

#define ISSUE_REF(i, R0, R1)                                                   \
  R0 = *(const float4*)(rrow + (size_t)(c0 + (i) * 2    ) * HW + x0);          \
  R1 = *(const float4*)(rrow + (size_t)(c0 + (i) * 2 + 1) * HW + x0);

  float4 ra0, ra1, rb0, rb1;
  // prologue: order G0, R0, G1 (ref older than next gll -> vmcnt(14) keeps depth)
  stage(0, 0);
  ISSUE_REF(0, ra0, ra1);
  stage(1, 1);

  for (int ii = 0; ii < 3; ++ii) {
    const int i = 2 * ii;
    // even chunk i: use ra, load ref(i+1)->rb
    ISSUE_REF(i + 1, rb0, rb1);
    stage(i + 2, (i + 2) % 3);
    asm volatile("s_waitcnt vmcnt(14)" ::: "memory");
    consume(i % 3, ra0, ra1);
    // odd chunk i+1: use rb, load ref(i+2)->ra
    ISSUE_REF(i + 2, ra0, ra1);
    stage(i + 3, (i + 3) % 3);
    asm volatile("s_waitcnt vmcnt(14)" ::: "memory");
    consume((i + 1) % 3, rb0, rb1);
  }
  // chunk 6: use ra(ref6), load ref7->rb, no more staging
  ISSUE_REF(7, rb0, rb1);
  asm volatile("s_waitcnt vmcnt(8)" ::: "memory");
  consume(0, ra0, ra1);     // 6 % 3
  // chunk 7
  asm volatile("s_waitcnt vmcnt(0)" ::: "memory");
  consume(1, rb0, rb1);     // 7 % 3
#undef ISSUE_REF

  // ---- one-shot cross-wave reduce through LDS (aliases staging region) ----
  __syncthreads();
#pragma unroll
  for (int k = 0; k < 9; ++k) {
    *(float4*)&smem[(k * 4 + wv) * 256 + x0]       = float4{dt[0][k], dt[1][k], dt[2][k], dt[3][k]};
    *(float4*)&smem[((9 + k) * 4 + wv) * 256 + x0] = float4{sq[0][k], sq[1][k], sq[2][k], sq[3][k]};
  }
  *(float4*)&smem[(18 * 4 + wv) * 256 + x0] = float4{sr4[0], sr4[1], sr4[2], sr4[3]};
  __syncthreads();

  // thread tid <-> pixel tid for the softmax/store phase
  float td[9], tq[9];
#pragma unroll
  for (int k = 0; k < 9; ++k) {
    td[k] = smem[(k * 4 + 0) * 256 + tid] + smem[(k * 4 + 1) * 256 + tid]
          + smem[(k * 4 + 2) * 256 + tid] + smem[(k * 4 + 3) * 256 + tid];
    tq[k] = smem[((9 + k) * 4 + 0) * 256 + tid] + smem[((9 + k) * 4 + 1) * 256 + tid]
          + smem[((9 + k) * 4 + 2) * 256 + tid] + smem[((9 + k) * 4 + 3) * 256 + tid];
  }
  const float tsr = smem[72 * 256 + tid] + smem[73 * 256 + tid]
                  + smem[74 * 256 + tid] + smem[75 * 256 + tid];

  const float invr = __frsqrt_rn(fmaxf(tsr, 1e-24f));
  float d[9], invp[9];
  float mx = -INFINITY;
#pragma unroll
  for (int k = 0; k < 9; ++k) {
    invp[k] = __frsqrt_rn(fmaxf(tq[k], 1e-24f));
    d[k]    = td[k] * invr * invp[k];
    mx      = fmaxf(mx, d[k]);
  }
  float s = 0.f;
  float cf[9];
#pragma unroll
  for (int k = 0; k < 9; ++k) {
    cf[k] = __expf(d[k] - mx);
    s += cf[k];
  }
  const float sinv = 1.0f / s;

  const int pix = by * W + tid;
#pragma unroll
  for (int k = 0; k < 9; ++k)
    coef[(size_t)k * PIX + pix] = cf[k] * sinv * invp[k];   // patch l2norm folded
}

// ---------------- K2: apply kernel (proven; XCD swizzle, grid=4096) ----------------
__global__ __launch_bounds__(256) void apply_kernel(const float* __restrict__ nbr,
                                                    const float* __restrict__ ref,
                                                    const float* __restrict__ coef,
                                                    float* __restrict__ out) {
  const int blk  = ((blockIdx.x & 7) << 9) | (blockIdx.x >> 3);  // bijective on [0,4096)
  const int gid  = blk * 256 + threadIdx.x;
  const int lane = gid & 63;
  const int x0   = lane * 4;
  const int t    = gid >> 6;
  const int y    = t & 255;
  const int u    = t >> 8;
  const int b    = u >> 5;
  const int c0   = (u & 31) * 2;

  const int ym = (y == 0)     ? 1     : y - 1;
  const int yp = (y == H - 1) ? H - 2 : y + 1;

  const float* n0  = nbr + ((size_t)b * C + c0) * HW;
  const float* n1  = n0 + HW;
  const float* r0p = ref + ((size_t)b * C + c0) * HW;
  float*       o0  = out + ((size_t)b * C + c0) * HW;

  const float4 a0 = *(const float4*)(n0 + ym * W + x0);
  const float4 a1 = *(const float4*)(n0 + y  * W + x0);
  const float4 a2 = *(const float4*)(n0 + yp * W + x0);
  const float4 b0 = *(const float4*)(n1 + ym * W + x0);
  const float4 b1 = *(const float4*)(n1 + y  * W + x0);
  const float4 b2 = *(const float4*)(n1 + yp * W + x0);
  const float4 f0 = *(const float4*)(r0p + y * W + x0);
  const float4 f1 = *(const float4*)(r0p + HW + y * W + x0);

  float La0 = __shfl(a0.w, lane - 1), Ra0 = __shfl(a0.x, lane + 1);
  float La1 = __shfl(a1.w, lane - 1), Ra1 = __shfl(a1.x, lane + 1);
  float La2 = __shfl(a2.w, lane - 1), Ra2 = __shfl(a2.x, lane + 1);
  float Lb0 = __shfl(b0.w, lane - 1), Rb0 = __shfl(b0.x, lane + 1);
  float Lb1 = __shfl(b1.w, lane - 1), Rb1 = __shfl(b1.x, lane + 1);
  float Lb2 = __shfl(b2.w, lane - 1), Rb2 = __shfl(b2.x, lane + 1);
  if (lane == 0)  { La0 = a0.y; La1 = a1.y; La2 = a2.y; Lb0 = b0.y; Lb1 = b1.y; Lb2 = b2.y; }
  if (lane == 63) { Ra0 = a0.z; Ra1 = a1.z; Ra2 = a2.z; Rb0 = b0.z; Rb1 = b1.z; Rb2 = b2.z; }

  float va[3][6] = {{La0, a0.x, a0.y, a0.z, a0.w, Ra0},
                    {La1, a1.x, a1.y, a1.z, a1.w, Ra1},
                    {La2, a2.x, a2.y, a2.z, a2.w, Ra2}};
  float vb[3][6] = {{Lb0, b0.x, b0.y, b0.z, b0.w, Rb0},
                    {Lb1, b1.x, b1.y, b1.z, b1.w, Rb1},
                    {Lb2, b2.x, b2.y, b2.z, b2.w, Rb2}};

  const int cbase = b * HW + y * W + x0;
  float aga[4] = {0.f, 0.f, 0.f, 0.f};
  float agb[4] = {0.f, 0.f, 0.f, 0.f};
#pragma unroll
  for (int k = 0; k < 9; ++k) {
    const float4 cf = *(const float4*)(coef + (size_t)k * PIX + cbase);
    const int r  = k / 3;
    const int cx = k % 3;
    const float cfe[4] = {cf.x, cf.y, cf.z, cf.w};
#pragma unroll
    for (int e = 0; e < 4; ++e) {
      aga[e] = fmaf(cfe[e], va[r][e + cx], aga[e]);
      agb[e] = fmaf(cfe[e], vb[r][e + cx], agb[e]);
    }
  }

  const float ctra[4] = {a1.x, a1.y, a1.z, a1.w};
  const float ctrb[4] = {b1.x, b1.y, b1.z, b1.w};
  const float rfa[4]  = {f0.x, f0.y, f0.z, f0.w};
  const float rfb[4]  = {f1.x, f1.y, f1.z, f1.w};
  float oae[4], obe[4];
#pragma unroll
  for (int e = 0; e < 4; ++e) {
    const float da = ctra[e] - rfa[e];
    const float db = ctrb[e] - rfb[e];
    oae[e] = aga[e] * __expf(-(da * da));
    obe[e] = agb[e] * __expf(-(db * db));
  }
  float4 oa, ob4;
  oa.x = oae[0]; oa.y = oae[1]; oa.z = oae[2]; oa.w = oae[3];
  ob4.x = obe[0]; ob4.y = obe[1]; ob4.z = obe[2]; ob4.w = obe[3];

  *(float4*)(o0 + y * W + x0) = oa;
  *(float4*)(o0 + HW + y * W + x0) = ob4;
}

// ---------------- fallback: R4 fused kernel (if ws too small) ----------------
__global__ __launch_bounds__(256) void fused_nbr_attn(const float* __restrict__ nbr,
                                                      const float* __restrict__ ref,
                                                      float* __restrict__ out) {
  const int tid  = threadIdx.x;
  const int lane = tid & 63;
  const int wv   = tid >> 6;
  const int px   = lane & 7;
  const int cg   = lane >> 3;

  const int pix = blockIdx.x * 32 + wv * 8 + px;
  const int b   = pix >> 16;
  const int p   = pix & (HW - 1);
  const int y   = p >> 8;
  const int x   = p & (W - 1);

  const int ym = (y == 0)     ? 1     : y - 1;
  const int yp = (y == H - 1) ? H - 2 : y + 1;
  const int xm = (x == 0)     ? 1     : x - 1;
  const int xp = (x == W - 1) ? W - 2 : x + 1;

  int off[9];
  off[0] = ym * W + xm; off[1] = ym * W + x; off[2] = ym * W + xp;
  off[3] = y  * W + xm; off[4] = y  * W + x; off[5] = y  * W + xp;
  off[6] = yp * W + xm; off[7] = yp * W + x; off[8] = yp * W + xp;
  const int ctr = y * W + x;

  const float* nb = nbr + ((size_t)b * C + cg * 8) * HW;
  const float* rb = ref + ((size_t)b * C + cg * 8) * HW;
  float*       ob = out + ((size_t)b * C + cg * 8) * HW;

  float v[8][9], r[8];
#pragma unroll
  for (int j = 0; j < 8; ++j) {
    r[j] = rb[j * HW + ctr];
#pragma unroll
    for (int k = 0; k < 9; ++k) v[j][k] = nb[j * HW + off[k]];
  }
  float sr = 0.f;
  float dot[9], ss[9];
#pragma unroll
  for (int k = 0; k < 9; ++k) { dot[k] = 0.f; ss[k] = 0.f; }
#pragma unroll
  for (int j = 0; j < 8; ++j) {
    sr = fmaf(r[j], r[j], sr);
#pragma unroll
    for (int k = 0; k < 9; ++k) {
      dot[k] = fmaf(r[j], v[j][k], dot[k]);
      ss[k]  = fmaf(v[j][k], v[j][k], ss[k]);
    }
  }
#pragma unroll
  for (int m = 8; m < 64; m <<= 1) {
    sr += __shfl_xor(sr, m);
#pragma unroll
    for (int k = 0; k < 9; ++k) {
      dot[k] += __shfl_xor(dot[k], m);
      ss[k]  += __shfl_xor(ss[k], m);
    }
  }
  const float invr = __frsqrt_rn(fmaxf(sr, 1e-24f));
  float d[9], invp[9];
  float mx = -INFINITY;
#pragma unroll
  for (int k = 0; k < 9; ++k) {
    invp[k] = __frsqrt_rn(fmaxf(ss[k], 1e-24f));
    d[k]    = dot[k] * invr * invp[k];
    mx      = fmaxf(mx, d[k]);
  }
  float s = 0.f;
  float coef[9];
#pragma unroll
  for (int k = 0; k < 9; ++k) {
    const float e = __expf(d[k] - mx);
    coef[k] = e;
    s += e;
  }
  const float sinv = 1.0f / s;
#pragma unroll
  for (int k = 0; k < 9; ++k) coef[k] *= sinv * invp[k];
#pragma unroll
  for (int j = 0; j < 8; ++j) {
    float a = 0.f;
#pragma unroll
    for (int k = 0; k < 9; ++k) a = fmaf(coef[k], v[j][k], a);
    const float diff = v[j][4] - r[j];
    const float wd   = __expf(-(diff * diff));
    ob[j * HW + ctr] = a * wd;
  }
}

extern "C" void kernel_launch(void* const* d_in, const int* in_sizes, int n_in,
                              void* d_out, int out_size, void* d_ws, size_t ws_size,
                              hipStream_t stream) {
  const float* nbr = (const float*)d_in[0];
  const float* ref = (const float*)d_in[1];
  float*       out = (float*)d_out;
  const size_t coef_bytes = (size_t)9 * PIX * sizeof(float);

  if (ws_size >= coef_bytes) {
    float* coef = (float*)d_ws;
    coef3_kernel<<<dim3(B * H), dim3(256), 0, stream>>>(nbr, ref, coef);     // 512 row-blocks
    apply_kernel<<<dim3(PIX / 4 * (C / 2) / 256), dim3(256), 0, stream>>>(nbr, ref, coef, out);  // 4096
  } else {
    fused_nbr_attn<<<dim3(PIX / 32), dim3(256), 0, stream>>>(nbr, ref, out);
  }
}

// Round 14
// 42.548 us; speedup vs baseline: 1.0377x; 1.0377x over previous
//
#include <hip/hip_runtime.h>
#include <stdint.h>

// Two-kernel 3x3 neighborhood-attention.
//  K1 coef4_kernel: block = one image row, 512 threads (8 waves). Within a
//    wave: lanes 0-31 and 32-63 cover the SAME 32 pixels but different
//    channel halves (h = lane>>5) -> 2x waves/SIMD vs R11 (the latency-hiding
//    fix; R12 falsified the barrier theory). Channels stream through
//    double-buffered LDS (CHUNK=8 -> 64 KB) via global_load_lds. Final
//    19 x __shfl_xor(32) reduce, softmax in lanes<32, coalesced stores.
//  K2 apply_kernel: float4 streaming out = exp(-(nbr-ref)^2)*sum_k coef_k*nbr_k.
// Shapes: [b=2, c=64, h=256, w=256] fp32.

constexpr int C = 64, H = 256, W = 256, HW = H * W;
constexpr int B = 2, PIX = B * HW;
constexpr int CHUNK = 8;            // channels per staged chunk
constexpr int NCHUNK = C / CHUNK;   // 8

typedef const __attribute__((address_space(1))) void* gas_ptr;
typedef __attribute__((address_space(3))) void* las_ptr;

// ---------------- K1: coefficient kernel (8-wave, ch-split) ----------------
__global__ __launch_bounds__(512) void coef4_kernel(const float* __restrict__ nbr,
                                                    const float* __restrict__ ref,
                                                    float* __restrict__ coef) {
  // buf[dbuf][ch][row: 0..2 = nbr @ {ym,y,yp}, 3 = ref @ y][W]  = 64 KB
  __shared__ float buf[2][CHUNK][4][W];

  const int tid  = threadIdx.x;       // 0..511
  const int lane = tid & 63;
  const int wid  = tid >> 6;          // wave 0..7
  const int h    = lane >> 5;         // channel half 0/1
  const int x    = (wid << 5) | (lane & 31);   // pixel 0..255

  // XCD band swizzle: 512 blocks, bijective
  const int by = ((blockIdx.x & 7) << 6) | (blockIdx.x >> 3);
  const int b  = by >> 8;
  const int y  = by & 255;
  const int ym = (y == 0)     ? 1     : y - 1;   // jnp reflect
  const int yp = (y == H - 1) ? H - 2 : y + 1;

  const float* nbase = nbr + (size_t)b * C * HW;
  const float* rbase = ref + (size_t)b * C * HW;
  const int rowoff[3] = {ym * W, y * W, yp * W};

  // stage chunk -> buf[bi]: 32 glls split 4 per wave (j = 4*wid + u)
  auto stage = [&](int chunk, int bi) {
#pragma unroll
    for (int u = 0; u < 4; ++u) {
      const int j   = 4 * wid + u;    // 0..31
      const int cc  = j >> 2;         // 0..7
      const int row = j & 3;          // 0..3
      const int c   = chunk * CHUNK + cc;
      const float* src = (row == 3)
          ? rbase + (size_t)c * HW + rowoff[1]
          : nbase + (size_t)c * HW + rowoff[row];
      __builtin_amdgcn_global_load_lds((gas_ptr)(src + lane * 4),
                                       (las_ptr)&buf[bi][cc][row][0], 16, 0, 0);
    }
  };

  const int xm = (x == 0)     ? 1     : x - 1;
  const int xp = (x == W - 1) ? W - 2 : x + 1;

  float sr = 0.f;
  float dot[9], ss[9];
#pragma unroll
  for (int k = 0; k < 9; ++k) { dot[k] = 0.f; ss[k] = 0.f; }

  stage(0, 0);
  __syncthreads();   // drains vmcnt -> chunk 0 visible

#pragma unroll 2
  for (int i = 0; i < NCHUNK; ++i) {
    const int bi = i & 1;
    if (i + 1 < NCHUNK) stage(i + 1, bi ^ 1);   // prefetch overlaps consume
#pragma unroll
    for (int q = 0; q < 4; ++q) {
      const int cc = h * 4 + q;       // this half's channel within the chunk
      const float r  = buf[bi][cc][3][x];
      const float v0 = buf[bi][cc][0][xm], v1 = buf[bi][cc][0][x], v2 = buf[bi][cc][0][xp];
      const float v3 = buf[bi][cc][1][xm], v4 = buf[bi][cc][1][x], v5 = buf[bi][cc][1][xp];
      const float v6 = buf[bi][cc][2][xm], v7 = buf[bi][cc][2][x], v8 = buf[bi][cc][2][xp];
      sr = fmaf(r, r, sr);
      dot[0] = fmaf(r, v0, dot[0]); ss[0] = fmaf(v0, v0, ss[0]);
      dot[1] = fmaf(r, v1, dot[1]); ss[1] = fmaf(v1, v1, ss[1]);
      dot[2] = fmaf(r, v2, dot[2]); ss[2] = fmaf(v2, v2, ss[2]);
      dot[3] = fmaf(r, v3, dot[3]); ss[3] = fmaf(v3, v3, ss[3]);
      dot[4] = fmaf(r, v4, dot[4]); ss[4] = fmaf(v4, v4, ss[4]);
      dot[5] = fmaf(r, v5, dot[5]); ss[5] = fmaf(v5, v5, ss[5]);
      dot[6] = fmaf(r, v6, dot[6]); ss[6] = fmaf(v6, v6, ss[6]);
      dot[7] = fmaf(r, v7, dot[7]); ss[7] = fmaf(v7, v7, ss[7]);
      dot[8] = fmaf(r, v8, dot[8]); ss[8] = fmaf(v8, v8, ss[8]);
    }
    __syncthreads();   // next chunk ready + protects dbuf reuse
  }

  // ---- combine the two channel halves (same pixel = lane ^ 32) ----
  sr += __shfl_xor(sr, 32);
#pragma unroll
  for (int k = 0; k < 9; ++k) {
    dot[k] += __shfl_xor(dot[k], 32);
    ss[k]  += __shfl_xor(ss[k], 32);
  }

  if (lane < 32) {
    // ---- normalize + softmax over the 9 neighbors ----
    const float invr = __frsqrt_rn(fmaxf(sr, 1e-24f));
    float d[9], invp[9];
    float mx = -INFINITY;
#pragma unroll
    for (int k = 0; k < 9; ++k) {
      invp[k] = __frsqrt_rn(fmaxf(ss[k], 1e-24f));
      d[k]    = dot[k] * invr * invp[k];
      mx      = fmaxf(mx, d[k]);
    }
    float s = 0.f;
    float cf[9];
#pragma unroll
    for (int k = 0; k < 9; ++k) {
      cf[k] = __expf(d[k] - mx);
      s += cf[k];
    }
    const float sinv = 1.0f / s;

    const int pix = by * W + x;       // b*HW + y*W + x
#pragma unroll
    for (int k = 0; k < 9; ++k)
      coef[(size_t)k * PIX + pix] = cf[k] * sinv * invp[k];   // patch l2norm folded
  }
}

// ---------------- K2: apply kernel (proven; XCD swizzle, grid=4096) ----------------
__global__ __launch_bounds__(256) void apply_kernel(const float* __restrict__ nbr,
                                                    const float* __restrict__ ref,
                                                    const float* __restrict__ coef,
                                                    float* __restrict__ out) {
  const int blk  = ((blockIdx.x & 7) << 9) | (blockIdx.x >> 3);  // bijective on [0,4096)
  const int gid  = blk * 256 + threadIdx.x;
  const int lane = gid & 63;
  const int x0   = lane * 4;
  const int t    = gid >> 6;
  const int y    = t & 255;
  const int u    = t >> 8;
  const int b    = u >> 5;
  const int c0   = (u & 31) * 2;

  const int ym = (y == 0)     ? 1     : y - 1;
  const int yp = (y == H - 1) ? H - 2 : y + 1;

  const float* n0  = nbr + ((size_t)b * C + c0) * HW;
  const float* n1  = n0 + HW;
  const float* r0p = ref + ((size_t)b * C + c0) * HW;
  float*       o0  = out + ((size_t)b * C + c0) * HW;

  const float4 a0 = *(const float4*)(n0 + ym * W + x0);
  const float4 a1 = *(const float4*)(n0 + y  * W + x0);
  const float4 a2 = *(const float4*)(n0 + yp * W + x0);
  const float4 b0 = *(const float4*)(n1 + ym * W + x0);
  const float4 b1 = *(const float4*)(n1 + y  * W + x0);
  const float4 b2 = *(const float4*)(n1 + yp * W + x0);
  const float4 f0 = *(const float4*)(r0p + y * W + x0);
  const float4 f1 = *(const float4*)(r0p + HW + y * W + x0);

  float La0 = __shfl(a0.w, lane - 1), Ra0 = __shfl(a0.x, lane + 1);
  float La1 = __shfl(a1.w, lane - 1), Ra1 = __shfl(a1.x, lane + 1);
  float La2 = __shfl(a2.w, lane - 1), Ra2 = __shfl(a2.x, lane + 1);
  float Lb0 = __shfl(b0.w, lane - 1), Rb0 = __shfl(b0.x, lane + 1);
  float Lb1 = __shfl(b1.w, lane - 1), Rb1 = __shfl(b1.x, lane + 1);
  float Lb2 = __shfl(b2.w, lane - 1), Rb2 = __shfl(b2.x, lane + 1);
  if (lane == 0)  { La0 = a0.y; La1 = a1.y; La2 = a2.y; Lb0 = b0.y; Lb1 = b1.y; Lb2 = b2.y; }
  if (lane == 63) { Ra0 = a0.z; Ra1 = a1.z; Ra2 = a2.z; Rb0 = b0.z; Rb1 = b1.z; Rb2 = b2.z; }

  float va[3][6] = {{La0, a0.x, a0.y, a0.z, a0.w, Ra0},
                    {La1, a1.x, a1.y, a1.z, a1.w, Ra1},
                    {La2, a2.x, a2.y, a2.z, a2.w, Ra2}};
  float vb[3][6] = {{Lb0, b0.x, b0.y, b0.z, b0.w, Rb0},
                    {Lb1, b1.x, b1.y, b1.z, b1.w, Rb1},
                    {Lb2, b2.x, b2.y, b2.z, b2.w, Rb2}};

  const int cbase = b * HW + y * W + x0;
  float aga[4] = {0.f, 0.f, 0.f, 0.f};
  float agb[4] = {0.f, 0.f, 0.f, 0.f};
#pragma unroll
  for (int k = 0; k < 9; ++k) {
    const float4 cf = *(const float4*)(coef + (size_t)k * PIX + cbase);
    const int r  = k / 3;
    const int cx = k % 3;
    const float cfe[4] = {cf.x, cf.y, cf.z, cf.w};
#pragma unroll
    for (int e = 0; e < 4; ++e) {
      aga[e] = fmaf(cfe[e], va[r][e + cx], aga[e]);
      agb[e] = fmaf(cfe[e], vb[r][e + cx], agb[e]);
    }
  }

  const float ctra[4] = {a1.x, a1.y, a1.z, a1.w};
  const float ctrb[4] = {b1.x, b1.y, b1.z, b1.w};
  const float rfa[4]  = {f0.x, f0.y, f0.z, f0.w};
  const float rfb[4]  = {f1.x, f1.y, f1.z, f1.w};
  float oae[4], obe[4];
#pragma unroll
  for (int e = 0; e < 4; ++e) {
    const float da = ctra[e] - rfa[e];
    const float db = ctrb[e] - rfb[e];
    oae[e] = aga[e] * __expf(-(da * da));
    obe[e] = agb[e] * __expf(-(db * db));
  }
  float4 oa, ob4;
  oa.x = oae[0]; oa.y = oae[1]; oa.z = oae[2]; oa.w = oae[3];
  ob4.x = obe[0]; ob4.y = obe[1]; ob4.z = obe[2]; ob4.w = obe[3];

  *(float4*)(o0 + y * W + x0) = oa;
  *(float4*)(o0 + HW + y * W + x0) = ob4;
}

// ---------------- fallback: R4 fused kernel (if ws too small) ----------------
__global__ __launch_bounds__(256) void fused_nbr_attn(const float* __restrict__ nbr,
                                                      const float* __restrict__ ref,
                                                      float* __restrict__ out) {
  const int tid  = threadIdx.x;
  const int lane = tid & 63;
  const int wv   = tid >> 6;
  const int px   = lane & 7;
  const int cg   = lane >> 3;

  const int pix = blockIdx.x * 32 + wv * 8 + px;
  const int b   = pix >> 16;
  const int p   = pix & (HW - 1);
  const int y   = p >> 8;
  const int x   = p & (W - 1);

  const int ym = (y == 0)     ? 1     : y - 1;
  const int yp = (y == H - 1) ? H - 2 : y + 1;
  const int xm = (x == 0)     ? 1     : x - 1;
  const int xp = (x == W - 1) ? W - 2 : x + 1;

  int off[9];
  off[0] = ym * W + xm; off[1] = ym * W + x; off[2] = ym * W + xp;
  off[3] = y  * W + xm; off[4] = y  * W + x; off[5] = y  * W + xp;
  off[6] = yp * W + xm; off[7] = yp * W + x; off[8] = yp * W + xp;
  const int ctr = y * W + x;

  const float* nb = nbr + ((size_t)b * C + cg * 8) * HW;
  const float* rb = ref + ((size_t)b * C + cg * 8) * HW;
  float*       ob = out + ((size_t)b * C + cg * 8) * HW;

  float v[8][9], r[8];
#pragma unroll
  for (int j = 0; j < 8; ++j) {
    r[j] = rb[j * HW + ctr];
#pragma unroll
    for (int k = 0; k < 9; ++k) v[j][k] = nb[j * HW + off[k]];
  }
  float sr = 0.f;
  float dot[9], ss[9];
#pragma unroll
  for (int k = 0; k < 9; ++k) { dot[k] = 0.f; ss[k] = 0.f; }
#pragma unroll
  for (int j = 0; j < 8; ++j) {
    sr = fmaf(r[j], r[j], sr);
#pragma unroll
    for (int k = 0; k < 9; ++k) {
      dot[k] = fmaf(r[j], v[j][k], dot[k]);
      ss[k]  = fmaf(v[j][k], v[j][k], ss[k]);
    }
  }
#pragma unroll
  for (int m = 8; m < 64; m <<= 1) {
    sr += __shfl_xor(sr, m);
#pragma unroll
    for (int k = 0; k < 9; ++k) {
      dot[k] += __shfl_xor(dot[k], m);
      ss[k]  += __shfl_xor(ss[k], m);
    }
  }
  const float invr = __frsqrt_rn(fmaxf(sr, 1e-24f));
  float d[9], invp[9];
  float mx = -INFINITY;
#pragma unroll
  for (int k = 0; k < 9; ++k) {
    invp[k] = __frsqrt_rn(fmaxf(ss[k], 1e-24f));
    d[k]    = dot[k] * invr * invp[k];
    mx      = fmaxf(mx, d[k]);
  }
  float s = 0.f;
  float coef[9];
#pragma unroll
  for (int k = 0; k < 9; ++k) {
    const float e = __expf(d[k] - mx);
    coef[k] = e;
    s += e;
  }
  const float sinv = 1.0f / s;
#pragma unroll
  for (int k = 0; k < 9; ++k) coef[k] *= sinv * invp[k];
#pragma unroll
  for (int j = 0; j < 8; ++j) {
    float a = 0.f;
#pragma unroll
    for (int k = 0; k < 9; ++k) a = fmaf(coef[k], v[j][k], a);
    const float diff = v[j][4] - r[j];
    const float wd   = __expf(-(diff * diff));
    ob[j * HW + ctr] = a * wd;
  }
}

extern "C" void kernel_launch(void* const* d_in, const int* in_sizes, int n_in,
                              void* d_out, int out_size, void* d_ws, size_t ws_size,
                              hipStream_t stream) {
  const float* nbr = (const float*)d_in[0];
  const float* ref = (const float*)d_in[1];
  float*       out = (float*)d_out;
  const size_t coef_bytes = (size_t)9 * PIX * sizeof(float);

  if (ws_size >= coef_bytes) {
    float* coef = (float*)d_ws;
    coef4_kernel<<<dim3(B * H), dim3(512), 0, stream>>>(nbr, ref, coef);     // 512 row-blocks, 8 waves
    apply_kernel<<<dim3(PIX / 4 * (C / 2) / 256), dim3(256), 0, stream>>>(nbr, ref, coef, out);  // 4096
  } else {
    fused_nbr_attn<<<dim3(PIX / 32), dim3(256), 0, stream>>>(nbr, ref, out);
  }
}

// Round 15
// 41.830 us; speedup vs baseline: 1.0555x; 1.0172x over previous
//
#include <hip/hip_runtime.h>
#include <stdint.h>

// Two-kernel 3x3 neighborhood-attention.
//  K1 coef5_kernel: apply-shaped loads + register accumulation.
//    Block = one image row, 4 waves; lane = quad (4 px), wave = 16-ch quarter.
//    Per channel: 3 nbr float4 + 1 ref float4 (1KB/wave-instr, fully
//    coalesced), x-margins via __shfl (no LDS staging, no hot-loop barriers).
//    76 register accumulators (dt[4][9], sq[4][9], sr[4]) force a real VGPR
//    allocation. One end reduce through LDS [19][4][256] + softmax + stores.
//  K2 apply_kernel: float4 streaming out = exp(-(nbr-ref)^2)*sum_k coef_k*nbr_k.
// Shapes: [b=2, c=64, h=256, w=256] fp32.

constexpr int C = 64, H = 256, W = 256, HW = H * W;
constexpr int B = 2, PIX = B * HW;

// ---------------- K1: coefficient kernel (apply-shaped) ----------------
__global__ __launch_bounds__(256) void coef5_kernel(const float* __restrict__ nbr,
                                                    const float* __restrict__ ref,
                                                    float* __restrict__ coef) {
  __shared__ float part[19][4][W];    // 77,824 B

  const int tid  = threadIdx.x;
  const int lane = tid & 63;          // quad index; x0 = 4*lane
  const int wv   = tid >> 6;          // channel quarter 0..3
  const int x0   = lane * 4;

  // XCD band swizzle: 512 blocks, bijective
  const int by = ((blockIdx.x & 7) << 6) | (blockIdx.x >> 3);
  const int b  = by >> 8;
  const int y  = by & 255;
  const int ym = (y == 0)     ? 1     : y - 1;   // jnp reflect
  const int yp = (y == H - 1) ? H - 2 : y + 1;

  const float* nbase = nbr + (size_t)b * C * HW;
  const float* rrow  = ref + (size_t)b * C * HW + y * W;
  const int oM = ym * W, oC = y * W, oP = yp * W;
  const int c0 = wv * 16;

  float dt[4][9], sq[4][9], sr[4];
#pragma unroll
  for (int e = 0; e < 4; ++e) {
    sr[e] = 0.f;
#pragma unroll
    for (int k = 0; k < 9; ++k) { dt[e][k] = 0.f; sq[e][k] = 0.f; }
  }

#pragma unroll 4
  for (int cc = 0; cc < 16; ++cc) {
    const float* cb = nbase + (size_t)(c0 + cc) * HW;
    const float4 am = *(const float4*)(cb + oM + x0);
    const float4 ac = *(const float4*)(cb + oC + x0);
    const float4 ap = *(const float4*)(cb + oP + x0);
    const float4 rf = *(const float4*)(rrow + (size_t)(c0 + cc) * HW + x0);
    const float rfe[4] = {rf.x, rf.y, rf.z, rf.w};

    sr[0] = fmaf(rfe[0], rfe[0], sr[0]);
    sr[1] = fmaf(rfe[1], rfe[1], sr[1]);
    sr[2] = fmaf(rfe[2], rfe[2], sr[2]);
    sr[3] = fmaf(rfe[3], rfe[3], sr[3]);

    const float4 rows[3] = {am, ac, ap};
#pragma unroll
    for (int r = 0; r < 3; ++r) {
      const float4 v = rows[r];
      float L = __shfl(v.w, lane - 1);
      float R = __shfl(v.x, lane + 1);
      if (lane == 0)  L = v.y;        // reflect: x=-1 -> 1
      if (lane == 63) R = v.z;        // reflect: x=256 -> 254
      const float win[6] = {L, v.x, v.y, v.z, v.w, R};
      float w2[6];
#pragma unroll
      for (int i = 0; i < 6; ++i) w2[i] = win[i] * win[i];
      const int kb = r * 3;
#pragma unroll
      for (int e = 0; e < 4; ++e) {
#pragma unroll
        for (int cx = 0; cx < 3; ++cx) {
          dt[e][kb + cx] = fmaf(rfe[e], win[e + cx], dt[e][kb + cx]);
          sq[e][kb + cx] += w2[e + cx];
        }
      }
    }
  }

  // ---- one-shot cross-wave reduce through LDS ----
#pragma unroll
  for (int k = 0; k < 9; ++k) {
    *(float4*)&part[k][wv][x0]     = float4{dt[0][k], dt[1][k], dt[2][k], dt[3][k]};
    *(float4*)&part[9 + k][wv][x0] = float4{sq[0][k], sq[1][k], sq[2][k], sq[3][k]};
  }
  // sr plane: pack the 4 px into plane 18
  *(float4*)&part[18][wv][x0] = float4{sr[0], sr[1], sr[2], sr[3]};
  __syncthreads();

  // thread tid <-> pixel tid for softmax/store
  float td[9], tq[9];
#pragma unroll
  for (int k = 0; k < 9; ++k) {
    td[k] = part[k][0][tid] + part[k][1][tid] + part[k][2][tid] + part[k][3][tid];
    tq[k] = part[9 + k][0][tid] + part[9 + k][1][tid] + part[9 + k][2][tid] + part[9 + k][3][tid];
  }
  const float tsr = part[18][0][tid] + part[18][1][tid] + part[18][2][tid] + part[18][3][tid];

  const float invr = __frsqrt_rn(fmaxf(tsr, 1e-24f));
  float d[9], invp[9];
  float mx = -INFINITY;
#pragma unroll
  for (int k = 0; k < 9; ++k) {
    invp[k] = __frsqrt_rn(fmaxf(tq[k], 1e-24f));
    d[k]    = td[k] * invr * invp[k];
    mx      = fmaxf(mx, d[k]);
  }
  float s = 0.f;
  float cf[9];
#pragma unroll
  for (int k = 0; k < 9; ++k) {
    cf[k] = __expf(d[k] - mx);
    s += cf[k];
  }
  const float sinv = 1.0f / s;

  const int pix = by * W + tid;
#pragma unroll
  for (int k = 0; k < 9; ++k)
    coef[(size_t)k * PIX + pix] = cf[k] * sinv * invp[k];   // patch l2norm folded
}

// ---------------- K2: apply kernel (proven; XCD swizzle, grid=4096) ----------------
__global__ __launch_bounds__(256) void apply_kernel(const float* __restrict__ nbr,
                                                    const float* __restrict__ ref,
                                                    const float* __restrict__ coef,
                                                    float* __restrict__ out) {
  const int blk  = ((blockIdx.x & 7) << 9) | (blockIdx.x >> 3);  // bijective on [0,4096)
  const int gid  = blk * 256 + threadIdx.x;
  const int lane = gid & 63;
  const int x0   = lane * 4;
  const int t    = gid >> 6;
  const int y    = t & 255;
  const int u    = t >> 8;
  const int b    = u >> 5;
  const int c0   = (u & 31) * 2;

  const int ym = (y == 0)     ? 1     : y - 1;
  const int yp = (y == H - 1) ? H - 2 : y + 1;

  const float* n0  = nbr + ((size_t)b * C + c0) * HW;
  const float* n1  = n0 + HW;
  const float* r0p = ref + ((size_t)b * C + c0) * HW;
  float*       o0  = out + ((size_t)b * C + c0) * HW;

  const float4 a0 = *(const float4*)(n0 + ym * W + x0);
  const float4 a1 = *(const float4*)(n0 + y  * W + x0);
  const float4 a2 = *(const float4*)(n0 + yp * W + x0);
  const float4 b0 = *(const float4*)(n1 + ym * W + x0);
  const float4 b1 = *(const float4*)(n1 + y  * W + x0);
  const float4 b2 = *(const float4*)(n1 + yp * W + x0);
  const float4 f0 = *(const float4*)(r0p + y * W + x0);
  const float4 f1 = *(const float4*)(r0p + HW + y * W + x0);

  float La0 = __shfl(a0.w, lane - 1), Ra0 = __shfl(a0.x, lane + 1);
  float La1 = __shfl(a1.w, lane - 1), Ra1 = __shfl(a1.x, lane + 1);
  float La2 = __shfl(a2.w, lane - 1), Ra2 = __shfl(a2.x, lane + 1);
  float Lb0 = __shfl(b0.w, lane - 1), Rb0 = __shfl(b0.x, lane + 1);
  float Lb1 = __shfl(b1.w, lane - 1), Rb1 = __shfl(b1.x, lane + 1);
  float Lb2 = __shfl(b2.w, lane - 1), Rb2 = __shfl(b2.x, lane + 1);
  if (lane == 0)  { La0 = a0.y; La1 = a1.y; La2 = a2.y; Lb0 = b0.y; Lb1 = b1.y; Lb2 = b2.y; }
  if (lane == 63) { Ra0 = a0.z; Ra1 = a1.z; Ra2 = a2.z; Rb0 = b0.z; Rb1 = b1.z; Rb2 = b2.z; }

  float va[3][6] = {{La0, a0.x, a0.y, a0.z, a0.w, Ra0},
                    {La1, a1.x, a1.y, a1.z, a1.w, Ra1},
                    {La2, a2.x, a2.y, a2.z, a2.w, Ra2}};
  float vb[3][6] = {{Lb0, b0.x, b0.y, b0.z, b0.w, Rb0},
                    {Lb1, b1.x, b1.y, b1.z, b1.w, Rb1},
                    {Lb2, b2.x, b2.y, b2.z, b2.w, Rb2}};

  const int cbase = b * HW + y * W + x0;
  float aga[4] = {0.f, 0.f, 0.f, 0.f};
  float agb[4] = {0.f, 0.f, 0.f, 0.f};
#pragma unroll
  for (int k = 0; k < 9; ++k) {
    const float4 cf = *(const float4*)(coef + (size_t)k * PIX + cbase);
    const int r  = k / 3;
    const int cx = k % 3;
    const float cfe[4] = {cf.x, cf.y, cf.z, cf.w};
#pragma unroll
    for (int e = 0; e < 4; ++e) {
      aga[e] = fmaf(cfe[e], va[r][e + cx], aga[e]);
      agb[e] = fmaf(cfe[e], vb[r][e + cx], agb[e]);
    }
  }

  const float ctra[4] = {a1.x, a1.y, a1.z, a1.w};
  const float ctrb[4] = {b1.x, b1.y, b1.z, b1.w};
  const float rfa[4]  = {f0.x, f0.y, f0.z, f0.w};
  const float rfb[4]  = {f1.x, f1.y, f1.z, f1.w};
  float oae[4], obe[4];
#pragma unroll
  for (int e = 0; e < 4; ++e) {
    const float da = ctra[e] - rfa[e];
    const float db = ctrb[e] - rfb[e];
    oae[e] = aga[e] * __expf(-(da * da));
    obe[e] = agb[e] * __expf(-(db * db));
  }
  float4 oa, ob4;
  oa.x = oae[0]; oa.y = oae[1]; oa.z = oae[2]; oa.w = oae[3];
  ob4.x = obe[0]; ob4.y = obe[1]; ob4.z = obe[2]; ob4.w = obe[3];

  *(float4*)(o0 + y * W + x0) = oa;
  *(float4*)(o0 + HW + y * W + x0) = ob4;
}

// ---------------- fallback: R4 fused kernel (if ws too small) ----------------
__global__ __launch_bounds__(256) void fused_nbr_attn(const float* __restrict__ nbr,
                                                      const float* __restrict__ ref,
                                                      float* __restrict__ out) {
  const int tid  = threadIdx.x;
  const int lane = tid & 63;
  const int wv   = tid >> 6;
  const int px   = lane & 7;
  const int cg   = lane >> 3;

  const int pix = blockIdx.x * 32 + wv * 8 + px;
  const int b   = pix >> 16;
  const int p   = pix & (HW - 1);
  const int y   = p >> 8;
  const int x   = p & (W - 1);

  const int ym = (y == 0)     ? 1     : y - 1;
  const int yp = (y == H - 1) ? H - 2 : y + 1;
  const int xm = (x == 0)     ? 1     : x - 1;
  const int xp = (x == W - 1) ? W - 2 : x + 1;

  int off[9];
  off[0] = ym * W + xm; off[1] = ym * W + x; off[2] = ym * W + xp;
  off[3] = y  * W + xm; off[4] = y  * W + x; off[5] = y  * W + xp;
  off[6] = yp * W + xm; off[7] = yp * W + x; off[8] = yp * W + xp;
  const int ctr = y * W + x;

  const float* nb = nbr + ((size_t)b * C + cg * 8) * HW;
  const float* rb = ref + ((size_t)b * C + cg * 8) * HW;
  float*       ob = out + ((size_t)b * C + cg * 8) * HW;

  float v[8][9], r[8];
#pragma unroll
  for (int j = 0; j < 8; ++j) {
    r[j] = rb[j * HW + ctr];
#pragma unroll
    for (int k = 0; k < 9; ++k) v[j][k] = nb[j * HW + off[k]];
  }
  float sr = 0.f;
  float dot[9], ss[9];
#pragma unroll
  for (int k = 0; k < 9; ++k) { dot[k] = 0.f; ss[k] = 0.f; }
#pragma unroll
  for (int j = 0; j < 8; ++j) {
    sr = fmaf(r[j], r[j], sr);
#pragma unroll
    for (int k = 0; k < 9; ++k) {
      dot[k] = fmaf(r[j], v[j][k], dot[k]);
      ss[k]  = fmaf(v[j][k], v[j][k], ss[k]);
    }
  }
#pragma unroll
  for (int m = 8; m < 64; m <<= 1) {
    sr += __shfl_xor(sr, m);
#pragma unroll
    for (int k = 0; k < 9; ++k) {
      dot[k] += __shfl_xor(dot[k], m);
      ss[k]  += __shfl_xor(ss[k], m);
    }
  }
  const float invr = __frsqrt_rn(fmaxf(sr, 1e-24f));
  float d[9], invp[9];
  float mx = -INFINITY;
#pragma unroll
  for (int k = 0; k < 9; ++k) {
    invp[k] = __frsqrt_rn(fmaxf(ss[k], 1e-24f));
    d[k]    = dot[k] * invr * invp[k];
    mx      = fmaxf(mx, d[k]);
  }
  float s = 0.f;
  float coef[9];
#pragma unroll
  for (int k = 0; k < 9; ++k) {
    const float e = __expf(d[k] - mx);
    coef[k] = e;
    s += e;
  }
  const float sinv = 1.0f / s;
#pragma unroll
  for (int k = 0; k < 9; ++k) coef[k] *= sinv * invp[k];
#pragma unroll
  for (int j = 0; j < 8; ++j) {
    float a = 0.f;
#pragma unroll
    for (int k = 0; k < 9; ++k) a = fmaf(coef[k], v[j][k], a);
    const float diff = v[j][4] - r[j];
    const float wd   = __expf(-(diff * diff));
    ob[j * HW + ctr] = a * wd;
  }
}

extern "C" void kernel_launch(void* const* d_in, const int* in_sizes, int n_in,
                              void* d_out, int out_size, void* d_ws, size_t ws_size,
                              hipStream_t stream) {
  const float* nbr = (const float*)d_in[0];
  const float* ref = (const float*)d_in[1];
  float*       out = (float*)d_out;
  const size_t coef_bytes = (size_t)9 * PIX * sizeof(float);

  if (ws_size >= coef_bytes) {
    float* coef = (float*)d_ws;
    coef5_kernel<<<dim3(B * H), dim3(256), 0, stream>>>(nbr, ref, coef);     // 512 row-blocks
    apply_kernel<<<dim3(PIX / 4 * (C / 2) / 256), dim3(256), 0, stream>>>(nbr, ref, coef, out);  // 4096
  } else {
    fused_nbr_attn<<<dim3(PIX / 32), dim3(256), 0, stream>>>(nbr, ref, out);
  }
}